// Round 1
// baseline (152.332 us; speedup 1.0000x reference)
//
#include <hip/hip_runtime.h>
#include <math.h>

#define PI_F 3.14159265358979323846f

typedef __attribute__((ext_vector_type(8))) short bf16x8;   // 8 bf16 (4 VGPRs)
typedef __attribute__((ext_vector_type(4))) float f32x4;    // MFMA C/D

__device__ inline unsigned short bf16rne(float f) {
    unsigned u = __float_as_uint(f);
    return (unsigned short)((u + 0x7FFFu + ((u >> 16) & 1u)) >> 16);
}

// ---------------------------------------------------------------------------
// Single fused kernel. Every block redundantly computes its own prep tables
// into LDS (no cross-block deps, no second dispatch, no serialization).
//
// LDS map (float offsets), 38960 floats = 155,840 B (< 160 KiB/CU, 1 blk/CU):
//   [0,7128)        xs staging bf16 [3][66][72]      -- dead after conv GEMM
//   [0,768)         fact[12][64]                     (post-conv overlay)
//   [1024,3328)     psi_bf [64][72] ushort           (post-conv overlay)
//   [3328,5632)     p_bf   [64][72] ushort           (post-conv overlay)
//   [8320,13504)    convres [64][81] fp32
//                   -- during conv GEMM: Bm ntile-4 [18][64][8] ushort (4608 f)
//   [13504,31936)   Bm ntiles 0-3 [4][18][64][8] ushort
//   [31936,34240)   Urb [64][72] ushort (stride 72: 2-way-free banks)
//   [34240,36544)   Uib [64][72] ushort
//   [36544,38848)   Zwc [64][72] ushort  ([c][t])
//   [38848,38896)   sang[48]
//   [38896,38960)   cb[64]
#define XS_OFF    0
#define FACT_OFF  0
#define PSI_OFF   1024
#define PBF_OFF   3328
#define CR_OFF    8320
#define BM_OFF    13504
#define URB_OFF   31936
#define UIB_OFF   34240
#define ZWC_OFF   36544
#define SANG_OFF  38848
#define CB_OFF    38896
#define SMEM_FLOATS 38960

__global__ __launch_bounds__(1024, 4) void k_all(
        const float* __restrict__ x,     const float* __restrict__ style,
        const float* __restrict__ dw,    const float* __restrict__ dpb,
        const float* __restrict__ s2dw,  const float* __restrict__ s2db,
        const float* __restrict__ qcnn,  const float* __restrict__ meas,
        const float* __restrict__ outw,  const float* __restrict__ outb,
        const float* __restrict__ rw,    const float* __restrict__ resb,
        float* __restrict__ out) {
    __shared__ __attribute__((aligned(16))) float smem[SMEM_FLOATS];
    unsigned*             xsu32 = (unsigned*)smem;
    const unsigned short* xsu   = (const unsigned short*)smem;
    float*          convres = smem + CR_OFF;
    float*          fact    = smem + FACT_OFF;
    unsigned short* psi_bf  = (unsigned short*)(smem + PSI_OFF);
    unsigned short* p_bf    = (unsigned short*)(smem + PBF_OFF);
    unsigned short* BmU     = (unsigned short*)(smem + BM_OFF);
    unsigned short* Bm4U    = (unsigned short*)(smem + CR_OFF);   // overlay
    unsigned short* Ur      = (unsigned short*)(smem + URB_OFF);
    unsigned short* Ui      = (unsigned short*)(smem + UIB_OFF);
    unsigned short* Zwc     = (unsigned short*)(smem + ZWC_OFF);
    float* s_sang = smem + SANG_OFF;
    float* s_cb   = smem + CB_OFF;

    int tid  = threadIdx.x;
    int lane = tid & 63;                 // pixel within block (== w)
    int wid  = __builtin_amdgcn_readfirstlane(tid >> 6);  // 0..15
    int m    = lane & 15;
    int quad = lane >> 4;

    int p = blockIdx.x * 64 + lane;      // pixel id: b*4096 + h*64 + w
    int b = p >> 12;
    int h = (p >> 6) & 63;
    int w = p & 63;
    const float* xb = x + (b << 18);

    // ================= phase 1: staging + all prep (one barrier) =========
    if (tid < 216) {  // zero xs halo: 3 rows x 2 cols x 36 uints
        int r3 = tid / 72, rest = tid % 72;
        int half = rest / 36, cp = rest % 36;
        xsu32[(r3 * 66 + half * 65) * 36 + cp] = 0u;
    }
    if (tid < 720) {  // zero Bm ntile-4 pad lanes (m = 6..15) -- disjoint from build
        int slab = tid / 40, r2 = tid % 40;
        int q4 = r2 / 10, mm = 6 + (r2 % 10);
        uint4 z = {0u, 0u, 0u, 0u};
        *(uint4*)(Bm4U + ((slab * 64 + (q4 << 4) + mm) << 3)) = z;
    }

    // ---- stage x-tile as bf16 (verbatim)
#pragma unroll
    for (int k = 0; k < 6; ++k) {
        int flat = k * 1024 + tid;       // 0..6143 = 3 rows x 32 cpairs x 64 w
        int row  = flat >> 11;
        int rem  = flat & 2047;
        int cp   = rem >> 6;
        int w2   = rem & 63;
        int hh   = h + row - 1;
        float v0 = 0.f, v1 = 0.f;
        if ((unsigned)hh < 64u) {
            const float* px = xb + (hh << 6) + w2;
            v0 = px[(2 * cp) << 12];
            v1 = px[(2 * cp + 1) << 12];
        }
        xsu32[(row * 66 + w2 + 1) * 36 + cp] =
            (unsigned)bf16rne(v0) | ((unsigned)bf16rne(v1) << 16);
    }

    // ---- Bm build: coalesced over W = [rw(64x576) ; dw(6x576)], scatter to LDS
#pragma unroll 4
    for (int it = 0; it < 40; ++it) {
        int flat = it * 1024 + tid;
        if (flat < 40320) {
            int n = flat / 576;
            int k = flat - n * 576;             // k = c*9 + ij
            float v = (n < 64) ? rw[flat] : dw[flat - 36864];
            int c  = k / 9;
            int ij = k - 9 * c;
            int slab = (ij << 1) | (c >> 5);
            int ln   = (((c >> 3) & 3) << 4) | (n & 15);
            int j    = c & 7;
            unsigned short* dst = (n < 64)
                ? (BmU  + (((n >> 4) * 1152 + slab * 64 + ln) << 3) + j)
                : (Bm4U + ((slab * 64 + ln) << 3) + j);
            *dst = bf16rne(v);
        }
    }

    // ---- circuit: each wave computes 4 columns simultaneously in registers
    {
        int s0 = wid * 4;
        float ar[4], ai[4];
#pragma unroll
        for (int cc = 0; cc < 4; ++cc) {
            ar[cc] = (lane == s0 + cc) ? 1.f : 0.f;
            ai[cc] = 0.f;
        }
#pragma unroll
        for (int l = 0; l < 2; ++l) {
#pragma unroll
            for (int wq = 0; wq < 6; ++wq) {
                int mask = 1 << (5 - wq);
                bool hi = (lane & mask) != 0;
                float th = qcnn[((l * 6 + wq) * 2 + 0) * 3];
                float sg, cg; sincosf(0.5f * th, &sg, &cg);
                float ph = qcnn[((l * 6 + wq) * 2 + 1) * 3];
                float sz, cz; sincosf(0.5f * ph, &sz, &cz);
                float szz = hi ? sz : -sz;
#pragma unroll
                for (int cc = 0; cc < 4; ++cc) {
                    float pr  = __shfl_xor(ar[cc], mask);
                    float pi2 = __shfl_xor(ai[cc], mask);
                    float nr = hi ? (sg * pr + cg * ar[cc]) : (cg * ar[cc] - sg * pr);
                    float ni = hi ? (sg * pi2 + cg * ai[cc]) : (cg * ai[cc] - sg * pi2);
                    ar[cc] = cz * nr - szz * ni;
                    ai[cc] = cz * ni + szz * nr;
                }
            }
#pragma unroll
            for (int wq = 0; wq < 6; ++wq) {  // ring CNOTs
                int cm = 1 << (5 - wq);
                int tm = 1 << (5 - ((wq + 1) % 6));
#pragma unroll
                for (int cc = 0; cc < 4; ++cc) {
                    float pr  = __shfl_xor(ar[cc], tm);
                    float pi2 = __shfl_xor(ai[cc], tm);
                    if (lane & cm) { ar[cc] = pr; ai[cc] = pi2; }
                }
            }
        }
#pragma unroll
        for (int wq = 0; wq < 6; ++wq) {  // U3 measurement basis
            int mask = 1 << (5 - wq);
            bool hi = (lane & mask) != 0;
            float th = meas[wq * 3 + 0], ph = meas[wq * 3 + 1], lm = meas[wq * 3 + 2];
            float st2, ct; sincosf(0.5f * th, &st2, &ct);
            float sl, cl;  sincosf(lm, &sl, &cl);
            float sp, cp;  sincosf(ph, &sp, &cp);
            float spl, cpl; sincosf(ph + lm, &spl, &cpl);
            float u01r = -cl * st2, u01i = -sl * st2;
            float u10r =  cp * st2, u10i =  sp * st2;
            float u11r =  cpl * ct, u11i =  spl * ct;
#pragma unroll
            for (int cc = 0; cc < 4; ++cc) {
                float pr  = __shfl_xor(ar[cc], mask);
                float pi2 = __shfl_xor(ai[cc], mask);
                float nr, ni;
                if (hi) {
                    nr = u10r * pr - u10i * pi2 + u11r * ar[cc] - u11i * ai[cc];
                    ni = u10r * pi2 + u10i * pr + u11r * ai[cc] + u11i * ar[cc];
                } else {
                    nr = ct * ar[cc] + u01r * pr - u01i * pi2;
                    ni = ct * ai[cc] + u01r * pi2 + u01i * pr;
                }
                ar[cc] = nr; ai[cc] = ni;
            }
        }
        unsigned short rr[4], ii[4];
#pragma unroll
        for (int cc = 0; cc < 4; ++cc) { rr[cc] = bf16rne(ar[cc]); ii[cc] = bf16rne(ai[cc]); }
        uint2 pr_ = make_uint2((unsigned)rr[0] | ((unsigned)rr[1] << 16),
                               (unsigned)rr[2] | ((unsigned)rr[3] << 16));
        uint2 pi_ = make_uint2((unsigned)ii[0] | ((unsigned)ii[1] << 16),
                               (unsigned)ii[2] | ((unsigned)ii[3] << 16));
        *(uint2*)(Ur + lane * 72 + s0) = pr_;
        *(uint2*)(Ui + lane * 72 + s0) = pi_;
    }

    // ---- Zw (transposed, stride 72): wave wid covers channels wid*4..+3
    {
        float zr[6];
#pragma unroll
        for (int q = 0; q < 6; ++q) zr[q] = ((lane >> (5 - q)) & 1) ? -1.f : 1.f;
#pragma unroll
        for (int cc = 0; cc < 4; ++cc) {
            int c = wid * 4 + cc;
            float z = 0.f;
#pragma unroll
            for (int q = 0; q < 6; ++q) z += outw[c * 6 + q] * zr[q];
            Zwc[c * 72 + lane] = bf16rne(z);
        }
    }
    if (wid == 6) s_cb[lane] = outb[lane] + resb[lane];
    if (wid == 7 && lane < 48) {   // style angles [b][q]
        int bb = lane / 6, q = lane % 6;
        float a = s2db[q];
#pragma unroll 8
        for (int j = 0; j < 128; ++j) a += style[bb * 128 + j] * s2dw[q * 128 + j];
        s_sang[lane] = tanhf(a) * PI_F;
    }
    __syncthreads();

    // ================= conv+angle MFMA GEMM (B from LDS) =================
    int mt0 = wid >> 2, nt0 = wid & 3;
    const unsigned short* a0base = xsu + (mt0 * 16 + m) * 72 + quad * 8;
    const unsigned short* b0base = BmU + (nt0 * 1152 + lane) * 8;
    f32x4 acc0 = {0.f, 0.f, 0.f, 0.f};
    f32x4 acc1 = {0.f, 0.f, 0.f, 0.f};
    if (wid < 4) {
        const unsigned short* a1base = xsu + (wid * 16 + m) * 72 + quad * 8;
        const unsigned short* b1base = Bm4U + lane * 8;
#pragma unroll
        for (int slab = 0; slab < 18; ++slab) {
            int ij = slab >> 1, i = ij / 3, j = ij - 3 * (ij / 3);
            int aoff = i * 4752 + j * 72 + (slab & 1) * 32;
            bf16x8 a0 = *(const bf16x8*)(a0base + aoff);
            bf16x8 b0 = *(const bf16x8*)(b0base + slab * 512);
            acc0 = __builtin_amdgcn_mfma_f32_16x16x32_bf16(a0, b0, acc0, 0, 0, 0);
            bf16x8 a1 = *(const bf16x8*)(a1base + aoff);
            bf16x8 b1 = *(const bf16x8*)(b1base + slab * 512);
            acc1 = __builtin_amdgcn_mfma_f32_16x16x32_bf16(a1, b1, acc1, 0, 0, 0);
        }
    } else {
#pragma unroll
        for (int slab = 0; slab < 18; ++slab) {
            int ij = slab >> 1, i = ij / 3, j = ij - 3 * (ij / 3);
            int aoff = i * 4752 + j * 72 + (slab & 1) * 32;
            bf16x8 a0 = *(const bf16x8*)(a0base + aoff);
            bf16x8 b0 = *(const bf16x8*)(b0base + slab * 512);
            acc0 = __builtin_amdgcn_mfma_f32_16x16x32_bf16(a0, b0, acc0, 0, 0, 0);
        }
    }
    // convres overlays Bm4 -> all waves must finish reading Bm before C-write
    __syncthreads();
#pragma unroll
    for (int r = 0; r < 4; ++r) {
        convres[(mt0 * 16 + quad * 4 + r) * 81 + nt0 * 16 + m] = acc0[r];
    }
    if (wid < 4) {
#pragma unroll
        for (int r = 0; r < 4; ++r) {
            convres[(wid * 16 + quad * 4 + r) * 81 + 64 + m] = acc1[r];
        }
    }
    __syncthreads();

    // ---- factors: waves 0-5 compute sincos(theta_q/2) for all 64 pixels
    if (wid < 6) {
        int q = wid;
        float t = convres[lane * 81 + 64 + q];
        float theta = tanhf(t + dpb[q]) * PI_F + s_sang[b * 6 + q];
        float sv, cv; sincosf(0.5f * theta, &sv, &cv);
        fact[q * 64 + lane] = sv;
        fact[(6 + q) * 64 + lane] = cv;
    }
    __syncthreads();

    // ---- psi (bf16): each wave builds states 4*wid..4*wid+3 for its pixel
    {
        float f0s = fact[0 * 64 + lane], f0c = fact[6 * 64 + lane];
        float f1s = fact[1 * 64 + lane], f1c = fact[7 * 64 + lane];
        float f2s = fact[2 * 64 + lane], f2c = fact[8 * 64 + lane];
        float f3s = fact[3 * 64 + lane], f3c = fact[9 * 64 + lane];
        float f4s = fact[4 * 64 + lane], f4c = fact[10 * 64 + lane];
        float f5s = fact[5 * 64 + lane], f5c = fact[11 * 64 + lane];
        int sb = wid * 4;
        float pre = (((sb >> 5) & 1) ? f0s : f0c)
                  * (((sb >> 4) & 1) ? f1s : f1c)
                  * (((sb >> 3) & 1) ? f2s : f2c)
                  * (((sb >> 2) & 1) ? f3s : f3c);
        unsigned short pk[4];
#pragma unroll
        for (int ti = 0; ti < 4; ++ti) {
            float v = pre * ((ti & 2) ? f4s : f4c) * ((ti & 1) ? f5s : f5c);
            pk[ti] = bf16rne(v);
        }
        *(uint2*)(psi_bf + lane * 72 + sb) =
            make_uint2((unsigned)pk[0] | ((unsigned)pk[1] << 16),
                       (unsigned)pk[2] | ((unsigned)pk[3] << 16));
    }
    __syncthreads();

    // ---- GEMM 1/2: Yr/Yi[pix][t] = psi[pix][s] @ U[t][s]^T  (U from LDS, stride 72)
    {
        const unsigned short* pa = psi_bf + (mt0 * 16 + m) * 72 + quad * 8;
        const unsigned short* ur = Ur + (nt0 * 16 + m) * 72 + quad * 8;
        const unsigned short* ui = Ui + (nt0 * 16 + m) * 72 + quad * 8;
        bf16x8 aA = *(const bf16x8*)(pa);
        bf16x8 aB = *(const bf16x8*)(pa + 32);
        f32x4 c1 = {0.f, 0.f, 0.f, 0.f};
        f32x4 c2 = {0.f, 0.f, 0.f, 0.f};
        c1 = __builtin_amdgcn_mfma_f32_16x16x32_bf16(aA, *(const bf16x8*)(ur), c1, 0, 0, 0);
        c1 = __builtin_amdgcn_mfma_f32_16x16x32_bf16(aB, *(const bf16x8*)(ur + 32), c1, 0, 0, 0);
        c2 = __builtin_amdgcn_mfma_f32_16x16x32_bf16(aA, *(const bf16x8*)(ui), c2, 0, 0, 0);
        c2 = __builtin_amdgcn_mfma_f32_16x16x32_bf16(aB, *(const bf16x8*)(ui + 32), c2, 0, 0, 0);
#pragma unroll
        for (int r = 0; r < 4; ++r) {
            float pv = c1[r] * c1[r] + c2[r] * c2[r];
            p_bf[(mt0 * 16 + quad * 4 + r) * 72 + nt0 * 16 + m] = bf16rne(pv);
        }
    }
    __syncthreads();

    // ---- GEMM 3: O[pix][c] = P[pix][t] @ Zw[t][c]  (Zw from LDS, stride 72)
    {
        const unsigned short* pa = p_bf + (mt0 * 16 + m) * 72 + quad * 8;
        const unsigned short* zc = Zwc + (nt0 * 16 + m) * 72 + quad * 8;
        f32x4 o = {0.f, 0.f, 0.f, 0.f};
        o = __builtin_amdgcn_mfma_f32_16x16x32_bf16(*(const bf16x8*)(pa),
                                                    *(const bf16x8*)(zc), o, 0, 0, 0);
        o = __builtin_amdgcn_mfma_f32_16x16x32_bf16(*(const bf16x8*)(pa + 32),
                                                    *(const bf16x8*)(zc + 32), o, 0, 0, 0);
#pragma unroll
        for (int r = 0; r < 4; ++r) {
            convres[(mt0 * 16 + quad * 4 + r) * 81 + nt0 * 16 + m] += o[r];
        }
    }
    __syncthreads();

    // ---- coalesced store: each wave stores 4 channels for all 64 pixels
    int ob = (b << 18) + (h << 6) + w;
#pragma unroll
    for (int kk = 0; kk < 4; ++kk) {
        int c = wid * 4 + kk;
        out[ob + (c << 12)] = convres[lane * 81 + c] + s_cb[c];
    }
}

// ---------------------------------------------------------------------------
extern "C" void kernel_launch(void* const* d_in, const int* in_sizes, int n_in,
                              void* d_out, int out_size, void* d_ws, size_t ws_size,
                              hipStream_t stream) {
    const float* x     = (const float*)d_in[0];
    const float* style = (const float*)d_in[1];
    const float* dw    = (const float*)d_in[2];
    const float* dpb   = (const float*)d_in[3];
    const float* s2dw  = (const float*)d_in[4];
    const float* s2db  = (const float*)d_in[5];
    const float* qcnn  = (const float*)d_in[6];
    const float* meas  = (const float*)d_in[7];
    const float* outw  = (const float*)d_in[8];
    const float* outb  = (const float*)d_in[9];
    const float* rw    = (const float*)d_in[10];
    const float* resb  = (const float*)d_in[11];
    float* out = (float*)d_out;

    hipLaunchKernelGGL(k_all, dim3(512), dim3(1024), 0, stream,
                       x, style, dw, dpb, s2dw, s2db, qcnn, meas,
                       outw, outb, rw, resb, out);
}

// Round 2
// 117.533 us; speedup vs baseline: 1.2961x; 1.2961x over previous
//
#include <hip/hip_runtime.h>
#include <math.h>

#define PI_F 3.14159265358979323846f

typedef __attribute__((ext_vector_type(8))) short bf16x8;   // 8 bf16 (4 VGPRs)
typedef __attribute__((ext_vector_type(4))) float f32x4;    // MFMA C/D

__device__ inline unsigned short bf16rne(float f) {
    unsigned u = __float_as_uint(f);
    return (unsigned short)((u + 0x7FFFu + ((u >> 16) & 1u)) >> 16);
}
__device__ inline float rlane(float v, int k) {
    return __uint_as_float(__builtin_amdgcn_readlane(__float_as_uint(v), k));
}

// ---------------------------------------------------------------------------
// Single fused kernel, 256 blocks x 1024 threads; each block: prep once, then
// TWO 64-pixel tiles sequentially (prep amortized, 1 block/CU, 1 round).
//
// LDS map (float offsets), 39496 floats = 157,984 B (< 160 KiB/CU):
//   [0,7128)        xs staging bf16 [3][66][72]      -- per-tile, re-staged
//   [0,768)         fact[12][64]                     (post-conv overlay)
//   [1024,3328)     psi_bf [64][72] ushort           (post-conv overlay)
//   [3328,5632)     p_bf   [64][72] ushort           (post-conv overlay)
//   [7128,12312)    convres [64][81] fp32
//   [12312,30744)   Bm ntiles 0-3 [4][18][64][8] ushort
//   [30744,32472)   Bm ntile 4 COMPACT [18][24][8] ushort (m<6 only)
//   [32472,34776)   Urb [64][72] ushort
//   [34776,37080)   Uib [64][72] ushort
//   [37080,39384)   Zwc [64][72] ushort  ([c][t])
//   [39384,39432)   sang[48]
//   [39432,39496)   cb[64]
#define XS_OFF    0
#define FACT_OFF  0
#define PSI_OFF   1024
#define PBF_OFF   3328
#define CR_OFF    7128
#define BM_OFF    12312
#define BM4_OFF   30744
#define URB_OFF   32472
#define UIB_OFF   34776
#define ZWC_OFF   37080
#define SANG_OFF  39384
#define CB_OFF    39432
#define SMEM_FLOATS 39496

__global__ __launch_bounds__(1024, 4) void k_all(
        const float* __restrict__ x,     const float* __restrict__ style,
        const float* __restrict__ dw,    const float* __restrict__ dpb,
        const float* __restrict__ s2dw,  const float* __restrict__ s2db,
        const float* __restrict__ qcnn,  const float* __restrict__ meas,
        const float* __restrict__ outw,  const float* __restrict__ outb,
        const float* __restrict__ rw,    const float* __restrict__ resb,
        float* __restrict__ out) {
    __shared__ __attribute__((aligned(16))) float smem[SMEM_FLOATS];
    unsigned*             xsu32 = (unsigned*)smem;
    const unsigned short* xsu   = (const unsigned short*)smem;
    float*          convres = smem + CR_OFF;
    float*          fact    = smem + FACT_OFF;
    unsigned short* psi_bf  = (unsigned short*)(smem + PSI_OFF);
    unsigned short* p_bf    = (unsigned short*)(smem + PBF_OFF);
    unsigned short* BmU     = (unsigned short*)(smem + BM_OFF);
    unsigned short* Bm4c    = (unsigned short*)(smem + BM4_OFF);
    unsigned short* Ur      = (unsigned short*)(smem + URB_OFF);
    unsigned short* Ui      = (unsigned short*)(smem + UIB_OFF);
    unsigned short* Zwc     = (unsigned short*)(smem + ZWC_OFF);
    float* s_sang = smem + SANG_OFF;
    float* s_cb   = smem + CB_OFF;

    int tid  = threadIdx.x;
    int lane = tid & 63;
    int wid  = __builtin_amdgcn_readfirstlane(tid >> 6);  // 0..15
    int m    = lane & 15;
    int quad = lane >> 4;

    // staging helper (tile row ht of batch image xbt)
    auto do_stage = [&](const float* xbt, int ht) {
        if (tid < 216) {  // zero halo: 3 rows x 2 cols x 36 uints
            int r3 = tid / 72, rest = tid % 72;
            int half = rest / 36, cp2 = rest % 36;
            xsu32[(r3 * 66 + half * 65) * 36 + cp2] = 0u;
        }
#pragma unroll
        for (int k = 0; k < 6; ++k) {
            int flat = k * 1024 + tid;   // 3 rows x 32 cpairs x 64 w
            int row  = flat >> 11;
            int rem  = flat & 2047;
            int cp2  = rem >> 6;
            int w2   = rem & 63;
            int hh   = ht + row - 1;
            float v0 = 0.f, v1 = 0.f;
            if ((unsigned)hh < 64u) {
                const float* px = xbt + (hh << 6) + w2;
                v0 = px[(2 * cp2) << 12];
                v1 = px[(2 * cp2 + 1) << 12];
            }
            xsu32[(row * 66 + w2 + 1) * 36 + cp2] =
                (unsigned)bf16rne(v0) | ((unsigned)bf16rne(v1) << 16);
        }
    };

    // ================= prologue: stage tile 0 + all prep ==================
    {
        int p0 = blockIdx.x * 128;
        do_stage(x + ((p0 >> 12) << 18), (p0 >> 6) & 63);
    }

    // ---- Bm build (R0 gather style: 8 strided reads -> one b128 LDS write)
#pragma unroll
    for (int it = 0; it < 5; ++it) {
        int entry = it * 1024 + tid;
        if (entry < 5040) {
            unsigned pk0, pk1, pk2, pk3;
            if (entry < 4608) {          // ntiles 0..3, full 64-lane fragments
                int nt   = entry / 1152;
                int rem  = entry - nt * 1152;
                int slab = rem >> 6;
                int ln   = rem & 63;
                int mm   = ln & 15, qq = ln >> 4;
                int n    = nt * 16 + mm;
                int ij   = slab >> 1;
                int ch   = (slab & 1) * 32 + qq * 8;
                const float* src = rw + n * 576 + ij;
                pk0 = (unsigned)bf16rne(src[(ch + 0) * 9]) | ((unsigned)bf16rne(src[(ch + 1) * 9]) << 16);
                pk1 = (unsigned)bf16rne(src[(ch + 2) * 9]) | ((unsigned)bf16rne(src[(ch + 3) * 9]) << 16);
                pk2 = (unsigned)bf16rne(src[(ch + 4) * 9]) | ((unsigned)bf16rne(src[(ch + 5) * 9]) << 16);
                pk3 = (unsigned)bf16rne(src[(ch + 6) * 9]) | ((unsigned)bf16rne(src[(ch + 7) * 9]) << 16);
                *(uint4*)(BmU + (entry << 3)) = make_uint4(pk0, pk1, pk2, pk3);
            } else {                     // ntile 4 compact: [18][24][8], m<6
                int e2   = entry - 4608;
                int slab = e2 / 24;
                int l24  = e2 - slab * 24;
                int qq   = l24 / 6;
                int mm   = l24 - qq * 6;
                int ij   = slab >> 1;
                int ch   = (slab & 1) * 32 + qq * 8;
                const float* src = dw + mm * 576 + ij;
                pk0 = (unsigned)bf16rne(src[(ch + 0) * 9]) | ((unsigned)bf16rne(src[(ch + 1) * 9]) << 16);
                pk1 = (unsigned)bf16rne(src[(ch + 2) * 9]) | ((unsigned)bf16rne(src[(ch + 3) * 9]) << 16);
                pk2 = (unsigned)bf16rne(src[(ch + 4) * 9]) | ((unsigned)bf16rne(src[(ch + 5) * 9]) << 16);
                pk3 = (unsigned)bf16rne(src[(ch + 6) * 9]) | ((unsigned)bf16rne(src[(ch + 7) * 9]) << 16);
                *(uint4*)(Bm4c + (e2 << 3)) = make_uint4(pk0, pk1, pk2, pk3);
            }
        }
    }

    // ---- lane-parallel trig table: one wave-wide sincos for all 48 gates
    float tsv, tcv;
    {
        int idx = lane < 48 ? lane : 0;
        float arg;
        if (idx < 24) {                      // gate g: 0.5 * qcnn[g*3]
            arg = 0.5f * qcnn[idx * 3];
        } else {                             // U3 wq = (idx-24)>>2, part = &3
            int q3 = (idx - 24) >> 2, part = (idx - 24) & 3;
            float th = meas[q3 * 3 + 0], ph = meas[q3 * 3 + 1], lm = meas[q3 * 3 + 2];
            arg = part == 0 ? 0.5f * th : part == 1 ? lm : part == 2 ? ph : ph + lm;
        }
        sincosf(arg, &tsv, &tcv);
    }

    // ---- circuit: each wave computes 4 columns (trig via readlane)
    {
        int s0 = wid * 4;
        float ar[4], ai[4];
#pragma unroll
        for (int cc = 0; cc < 4; ++cc) {
            ar[cc] = (lane == s0 + cc) ? 1.f : 0.f;
            ai[cc] = 0.f;
        }
#pragma unroll
        for (int l = 0; l < 2; ++l) {
#pragma unroll
            for (int wq = 0; wq < 6; ++wq) {
                int mask = 1 << (5 - wq);
                bool hi = (lane & mask) != 0;
                int g = (l * 6 + wq) * 2;
                float sg = rlane(tsv, g),     cg = rlane(tcv, g);
                float sz = rlane(tsv, g + 1), cz = rlane(tcv, g + 1);
                float szz = hi ? sz : -sz;
#pragma unroll
                for (int cc = 0; cc < 4; ++cc) {
                    float pr  = __shfl_xor(ar[cc], mask);
                    float pi2 = __shfl_xor(ai[cc], mask);
                    float nr = hi ? (sg * pr + cg * ar[cc]) : (cg * ar[cc] - sg * pr);
                    float ni = hi ? (sg * pi2 + cg * ai[cc]) : (cg * ai[cc] - sg * pi2);
                    ar[cc] = cz * nr - szz * ni;
                    ai[cc] = cz * ni + szz * nr;
                }
            }
#pragma unroll
            for (int wq = 0; wq < 6; ++wq) {  // ring CNOTs
                int cm = 1 << (5 - wq);
                int tm = 1 << (5 - ((wq + 1) % 6));
#pragma unroll
                for (int cc = 0; cc < 4; ++cc) {
                    float pr  = __shfl_xor(ar[cc], tm);
                    float pi2 = __shfl_xor(ai[cc], tm);
                    if (lane & cm) { ar[cc] = pr; ai[cc] = pi2; }
                }
            }
        }
#pragma unroll
        for (int wq = 0; wq < 6; ++wq) {  // U3 measurement basis
            int mask = 1 << (5 - wq);
            bool hi = (lane & mask) != 0;
            int u = 24 + wq * 4;
            float st2 = rlane(tsv, u),     ct  = rlane(tcv, u);
            float sl  = rlane(tsv, u + 1), cl  = rlane(tcv, u + 1);
            float sp  = rlane(tsv, u + 2), cp  = rlane(tcv, u + 2);
            float spl = rlane(tsv, u + 3), cpl = rlane(tcv, u + 3);
            float u01r = -cl * st2, u01i = -sl * st2;
            float u10r =  cp * st2, u10i =  sp * st2;
            float u11r =  cpl * ct, u11i =  spl * ct;
#pragma unroll
            for (int cc = 0; cc < 4; ++cc) {
                float pr  = __shfl_xor(ar[cc], mask);
                float pi2 = __shfl_xor(ai[cc], mask);
                float nr, ni;
                if (hi) {
                    nr = u10r * pr - u10i * pi2 + u11r * ar[cc] - u11i * ai[cc];
                    ni = u10r * pi2 + u10i * pr + u11r * ai[cc] + u11i * ar[cc];
                } else {
                    nr = ct * ar[cc] + u01r * pr - u01i * pi2;
                    ni = ct * ai[cc] + u01r * pi2 + u01i * pr;
                }
                ar[cc] = nr; ai[cc] = ni;
            }
        }
        unsigned short rr[4], ii[4];
#pragma unroll
        for (int cc = 0; cc < 4; ++cc) { rr[cc] = bf16rne(ar[cc]); ii[cc] = bf16rne(ai[cc]); }
        *(uint2*)(Ur + lane * 72 + s0) =
            make_uint2((unsigned)rr[0] | ((unsigned)rr[1] << 16),
                       (unsigned)rr[2] | ((unsigned)rr[3] << 16));
        *(uint2*)(Ui + lane * 72 + s0) =
            make_uint2((unsigned)ii[0] | ((unsigned)ii[1] << 16),
                       (unsigned)ii[2] | ((unsigned)ii[3] << 16));
    }

    // ---- Zw (transposed, stride 72): wave wid covers channels wid*4..+3
    {
        float zr[6];
#pragma unroll
        for (int q = 0; q < 6; ++q) zr[q] = ((lane >> (5 - q)) & 1) ? -1.f : 1.f;
#pragma unroll
        for (int cc = 0; cc < 4; ++cc) {
            int c = wid * 4 + cc;
            float z = 0.f;
#pragma unroll
            for (int q = 0; q < 6; ++q) z += outw[c * 6 + q] * zr[q];
            Zwc[c * 72 + lane] = bf16rne(z);
        }
    }
    if (wid == 6) s_cb[lane] = outb[lane] + resb[lane];
    if (wid == 7 && lane < 48) {   // style angles [b][q]
        int bb = lane / 6, q = lane % 6;
        float a = s2db[q];
#pragma unroll 8
        for (int j = 0; j < 128; ++j) a += style[bb * 128 + j] * s2dw[q * 128 + j];
        s_sang[lane] = tanhf(a) * PI_F;
    }
    __syncthreads();

    // ================= two tiles, sequential ==============================
    int mt0 = wid >> 2, nt0 = wid & 3;
    const unsigned short* a0base = xsu + (mt0 * 16 + m) * 72 + quad * 8;
    const unsigned short* b0base = BmU + ((nt0 * 18) * 64 + lane) * 8;
    const unsigned short* a1base = xsu + (wid * 16 + m) * 72 + quad * 8;   // waves 0-3
    int l24c = quad * 6 + (m < 6 ? m : 0);
    const unsigned short* b1base = Bm4c + (l24c << 3);
    const bf16x8 zv = {0, 0, 0, 0, 0, 0, 0, 0};

    for (int t = 0; t < 2; ++t) {
        int pt = blockIdx.x * 128 + t * 64;
        int bt = pt >> 12;
        int ht = (pt >> 6) & 63;

        // ---- conv+angle MFMA GEMM (A: xs, B: Bm -- both LDS)
        f32x4 acc0 = {0.f, 0.f, 0.f, 0.f};
        f32x4 acc1 = {0.f, 0.f, 0.f, 0.f};
        if (wid < 4) {
#pragma unroll
            for (int slab = 0; slab < 18; ++slab) {
                int ij = slab >> 1, i = ij / 3, j = ij - 3 * (ij / 3);
                int aoff = i * 4752 + j * 72 + (slab & 1) * 32;
                bf16x8 a0 = *(const bf16x8*)(a0base + aoff);
                bf16x8 b0 = *(const bf16x8*)(b0base + slab * 512);
                acc0 = __builtin_amdgcn_mfma_f32_16x16x32_bf16(a0, b0, acc0, 0, 0, 0);
                bf16x8 a1 = *(const bf16x8*)(a1base + aoff);
                bf16x8 b1 = *(const bf16x8*)(b1base + slab * 192);
                if (m >= 6) b1 = zv;
                acc1 = __builtin_amdgcn_mfma_f32_16x16x32_bf16(a1, b1, acc1, 0, 0, 0);
            }
        } else {
#pragma unroll
            for (int slab = 0; slab < 18; ++slab) {
                int ij = slab >> 1, i = ij / 3, j = ij - 3 * (ij / 3);
                int aoff = i * 4752 + j * 72 + (slab & 1) * 32;
                bf16x8 a0 = *(const bf16x8*)(a0base + aoff);
                bf16x8 b0 = *(const bf16x8*)(b0base + slab * 512);
                acc0 = __builtin_amdgcn_mfma_f32_16x16x32_bf16(a0, b0, acc0, 0, 0, 0);
            }
        }
        // C/D layout: col = lane&15 (=n), row = quad*4 + reg (=pixel)
#pragma unroll
        for (int r = 0; r < 4; ++r) {
            convres[(mt0 * 16 + quad * 4 + r) * 81 + nt0 * 16 + m] = acc0[r];
        }
        if (wid < 4) {
#pragma unroll
            for (int r = 0; r < 4; ++r) {
                convres[(wid * 16 + quad * 4 + r) * 81 + 64 + m] = acc1[r];
            }
        }
        __syncthreads();

        // ---- factors: waves 0-5 compute sincos(theta_q/2) for all 64 pixels
        if (wid < 6) {
            int q = wid;
            float tv = convres[lane * 81 + 64 + q];
            float theta = tanhf(tv + dpb[q]) * PI_F + s_sang[bt * 6 + q];
            float sv, cv; sincosf(0.5f * theta, &sv, &cv);
            fact[q * 64 + lane] = sv;
            fact[(6 + q) * 64 + lane] = cv;
        }
        __syncthreads();

        // ---- psi (bf16): each wave builds states 4*wid..4*wid+3 for its pixel
        {
            float f0s = fact[0 * 64 + lane], f0c = fact[6 * 64 + lane];
            float f1s = fact[1 * 64 + lane], f1c = fact[7 * 64 + lane];
            float f2s = fact[2 * 64 + lane], f2c = fact[8 * 64 + lane];
            float f3s = fact[3 * 64 + lane], f3c = fact[9 * 64 + lane];
            float f4s = fact[4 * 64 + lane], f4c = fact[10 * 64 + lane];
            float f5s = fact[5 * 64 + lane], f5c = fact[11 * 64 + lane];
            int sb = wid * 4;
            float pre = (((sb >> 5) & 1) ? f0s : f0c)
                      * (((sb >> 4) & 1) ? f1s : f1c)
                      * (((sb >> 3) & 1) ? f2s : f2c)
                      * (((sb >> 2) & 1) ? f3s : f3c);
            unsigned short pk[4];
#pragma unroll
            for (int ti = 0; ti < 4; ++ti) {
                float v = pre * ((ti & 2) ? f4s : f4c) * ((ti & 1) ? f5s : f5c);
                pk[ti] = bf16rne(v);
            }
            *(uint2*)(psi_bf + lane * 72 + sb) =
                make_uint2((unsigned)pk[0] | ((unsigned)pk[1] << 16),
                           (unsigned)pk[2] | ((unsigned)pk[3] << 16));
        }
        __syncthreads();

        // ---- GEMM 1/2: Yr/Yi[pix][t] = psi[pix][s] @ U[t][s]^T
        {
            const unsigned short* pa = psi_bf + (mt0 * 16 + m) * 72 + quad * 8;
            const unsigned short* ur = Ur + (nt0 * 16 + m) * 72 + quad * 8;
            const unsigned short* ui = Ui + (nt0 * 16 + m) * 72 + quad * 8;
            bf16x8 aA = *(const bf16x8*)(pa);
            bf16x8 aB = *(const bf16x8*)(pa + 32);
            f32x4 c1 = {0.f, 0.f, 0.f, 0.f};
            f32x4 c2 = {0.f, 0.f, 0.f, 0.f};
            c1 = __builtin_amdgcn_mfma_f32_16x16x32_bf16(aA, *(const bf16x8*)(ur), c1, 0, 0, 0);
            c1 = __builtin_amdgcn_mfma_f32_16x16x32_bf16(aB, *(const bf16x8*)(ur + 32), c1, 0, 0, 0);
            c2 = __builtin_amdgcn_mfma_f32_16x16x32_bf16(aA, *(const bf16x8*)(ui), c2, 0, 0, 0);
            c2 = __builtin_amdgcn_mfma_f32_16x16x32_bf16(aB, *(const bf16x8*)(ui + 32), c2, 0, 0, 0);
#pragma unroll
            for (int r = 0; r < 4; ++r) {
                float pv = c1[r] * c1[r] + c2[r] * c2[r];
                p_bf[(mt0 * 16 + quad * 4 + r) * 72 + nt0 * 16 + m] = bf16rne(pv);
            }
        }
        __syncthreads();

        // ---- GEMM 3: O[pix][c] = P[pix][t] @ Zw[t][c], accumulate
        {
            const unsigned short* pa = p_bf + (mt0 * 16 + m) * 72 + quad * 8;
            const unsigned short* zc = Zwc + (nt0 * 16 + m) * 72 + quad * 8;
            f32x4 o = {0.f, 0.f, 0.f, 0.f};
            o = __builtin_amdgcn_mfma_f32_16x16x32_bf16(*(const bf16x8*)(pa),
                                                        *(const bf16x8*)(zc), o, 0, 0, 0);
            o = __builtin_amdgcn_mfma_f32_16x16x32_bf16(*(const bf16x8*)(pa + 32),
                                                        *(const bf16x8*)(zc + 32), o, 0, 0, 0);
#pragma unroll
            for (int r = 0; r < 4; ++r) {
                convres[(mt0 * 16 + quad * 4 + r) * 81 + nt0 * 16 + m] += o[r];
            }
        }
        __syncthreads();

        // ---- coalesced store: each wave stores 4 channels for all 64 pixels
        int ob = (bt << 18) + (ht << 6) + lane;
#pragma unroll
        for (int kk = 0; kk < 4; ++kk) {
            int c = wid * 4 + kk;
            out[ob + (c << 12)] = convres[lane * 81 + c] + s_cb[c];
        }

        if (t == 0) {   // stage tile 1 (xs region free: p_bf/fact dead after G3)
            int p1 = blockIdx.x * 128 + 64;
            do_stage(x + ((p1 >> 12) << 18), (p1 >> 6) & 63);
            __syncthreads();
        }
    }
}

// ---------------------------------------------------------------------------
extern "C" void kernel_launch(void* const* d_in, const int* in_sizes, int n_in,
                              void* d_out, int out_size, void* d_ws, size_t ws_size,
                              hipStream_t stream) {
    const float* x     = (const float*)d_in[0];
    const float* style = (const float*)d_in[1];
    const float* dw    = (const float*)d_in[2];
    const float* dpb   = (const float*)d_in[3];
    const float* s2dw  = (const float*)d_in[4];
    const float* s2db  = (const float*)d_in[5];
    const float* qcnn  = (const float*)d_in[6];
    const float* meas  = (const float*)d_in[7];
    const float* outw  = (const float*)d_in[8];
    const float* outb  = (const float*)d_in[9];
    const float* rw    = (const float*)d_in[10];
    const float* resb  = (const float*)d_in[11];
    float* out = (float*)d_out;

    hipLaunchKernelGGL(k_all, dim3(256), dim3(1024), 0, stream,
                       x, style, dw, dpb, s2dw, s2db, qcnn, meas,
                       outw, outb, rw, resb, out);
}

// Round 3
// 114.492 us; speedup vs baseline: 1.3305x; 1.0266x over previous
//
#include <hip/hip_runtime.h>
#include <hip/hip_cooperative_groups.h>
#include <math.h>

#define PI_F 3.14159265358979323846f

typedef __attribute__((ext_vector_type(8))) short bf16x8;   // 8 bf16 (4 VGPRs)
typedef __attribute__((ext_vector_type(4))) float f32x4;    // MFMA C/D

namespace cg = cooperative_groups;

// Persistent device tables (rewritten fully every launch; input-deterministic,
// so even a stale cross-XCD read would see identical values).
__device__ float g_sang[48];       // style angles [b][q] (tanh*pi applied)
__device__ float g_cb[64];         // out_proj_b + res_proj_b
__device__ __attribute__((aligned(16))) unsigned short g_Urb[64 * 64];  // [t][s]
__device__ __attribute__((aligned(16))) unsigned short g_Uib[64 * 64];  // [t][s]
__device__ __attribute__((aligned(16))) unsigned short g_Zwc[64 * 64];  // [c][t]
// MFMA B operand for conv GEMM: [ntile(5)][slab(18)][lane(64)][j(8)]
__device__ __attribute__((aligned(16))) unsigned short g_Bm[5 * 18 * 64 * 8];

__device__ inline unsigned short bf16rne(float f) {
    unsigned u = __float_as_uint(f);
    return (unsigned short)((u + 0x7FFFu + ((u >> 16) & 1u)) >> 16);
}
__device__ inline float rlane(float v, int k) {
    return __uint_as_float(__builtin_amdgcn_readlane(__float_as_uint(v), k));
}

// ---------------------------------------------------------------------------
// Phase A: all prep, distributed across (at least 11) 1024-thread blocks.
static __device__ void phaseA(const float* __restrict__ style,
                              const float* __restrict__ dw,
                              const float* __restrict__ rw,
                              const float* __restrict__ s2dw,
                              const float* __restrict__ s2db,
                              const float* __restrict__ qcnn,
                              const float* __restrict__ meas,
                              const float* __restrict__ outw,
                              const float* __restrict__ outb,
                              const float* __restrict__ resb) {
    int tid  = threadIdx.x;
    int lane = tid & 63;
    int wid  = tid >> 6;
    int gtid = blockIdx.x * 1024 + tid;

    // ---- Bm build: blocks 0..5, one fragment-entry per thread (16 B store)
    if (gtid < 5760) {
        int nt   = gtid / 1152;
        int rem  = gtid - nt * 1152;
        int slab = rem >> 6;
        int ln   = rem & 63;
        int mm   = ln & 15, qq = ln >> 4;
        int n    = nt * 16 + mm;
        int ij   = slab >> 1;
        int ch   = (slab & 1) * 32 + qq * 8;
        unsigned pk[4] = {0u, 0u, 0u, 0u};
        if (n < 70) {
            const float* src = (n < 64) ? (rw + n * 576 + ij) : (dw + (n - 64) * 576 + ij);
#pragma unroll
            for (int jj = 0; jj < 4; ++jj) {
                pk[jj] = (unsigned)bf16rne(src[(ch + 2 * jj) * 9])
                       | ((unsigned)bf16rne(src[(ch + 2 * jj + 1) * 9]) << 16);
            }
        }
        *(uint4*)(g_Bm + gtid * 8) = make_uint4(pk[0], pk[1], pk[2], pk[3]);
    }

    if (blockIdx.x == 8) {
        // ---- circuit: lane-parallel trig table, then 4 columns per wave
        float tsv, tcv;
        {
            int idx = lane < 48 ? lane : 0;
            float arg;
            if (idx < 24) {
                arg = 0.5f * qcnn[idx * 3];
            } else {
                int q3 = (idx - 24) >> 2, part = (idx - 24) & 3;
                float th = meas[q3 * 3 + 0], ph = meas[q3 * 3 + 1], lm = meas[q3 * 3 + 2];
                arg = part == 0 ? 0.5f * th : part == 1 ? lm : part == 2 ? ph : ph + lm;
            }
            sincosf(arg, &tsv, &tcv);
        }
        int s0 = wid * 4;
        float ar[4], ai[4];
#pragma unroll
        for (int cc = 0; cc < 4; ++cc) {
            ar[cc] = (lane == s0 + cc) ? 1.f : 0.f;
            ai[cc] = 0.f;
        }
#pragma unroll
        for (int l = 0; l < 2; ++l) {
#pragma unroll
            for (int wq = 0; wq < 6; ++wq) {
                int mask = 1 << (5 - wq);
                bool hi = (lane & mask) != 0;
                int g = (l * 6 + wq) * 2;
                float sg = rlane(tsv, g),     cg = rlane(tcv, g);
                float sz = rlane(tsv, g + 1), cz = rlane(tcv, g + 1);
                float szz = hi ? sz : -sz;
#pragma unroll
                for (int cc = 0; cc < 4; ++cc) {
                    float pr  = __shfl_xor(ar[cc], mask);
                    float pi2 = __shfl_xor(ai[cc], mask);
                    float nr = hi ? (sg * pr + cg * ar[cc]) : (cg * ar[cc] - sg * pr);
                    float ni = hi ? (sg * pi2 + cg * ai[cc]) : (cg * ai[cc] - sg * pi2);
                    ar[cc] = cz * nr - szz * ni;
                    ai[cc] = cz * ni + szz * nr;
                }
            }
#pragma unroll
            for (int wq = 0; wq < 6; ++wq) {  // ring CNOTs
                int cm = 1 << (5 - wq);
                int tm = 1 << (5 - ((wq + 1) % 6));
#pragma unroll
                for (int cc = 0; cc < 4; ++cc) {
                    float pr  = __shfl_xor(ar[cc], tm);
                    float pi2 = __shfl_xor(ai[cc], tm);
                    if (lane & cm) { ar[cc] = pr; ai[cc] = pi2; }
                }
            }
        }
#pragma unroll
        for (int wq = 0; wq < 6; ++wq) {  // U3 measurement basis
            int mask = 1 << (5 - wq);
            bool hi = (lane & mask) != 0;
            int u = 24 + wq * 4;
            float st2 = rlane(tsv, u),     ct  = rlane(tcv, u);
            float sl  = rlane(tsv, u + 1), cl  = rlane(tcv, u + 1);
            float sp  = rlane(tsv, u + 2), cp  = rlane(tcv, u + 2);
            float spl = rlane(tsv, u + 3), cpl = rlane(tcv, u + 3);
            float u01r = -cl * st2, u01i = -sl * st2;
            float u10r =  cp * st2, u10i =  sp * st2;
            float u11r =  cpl * ct, u11i =  spl * ct;
#pragma unroll
            for (int cc = 0; cc < 4; ++cc) {
                float pr  = __shfl_xor(ar[cc], mask);
                float pi2 = __shfl_xor(ai[cc], mask);
                float nr, ni;
                if (hi) {
                    nr = u10r * pr - u10i * pi2 + u11r * ar[cc] - u11i * ai[cc];
                    ni = u10r * pi2 + u10i * pr + u11r * ai[cc] + u11i * ar[cc];
                } else {
                    nr = ct * ar[cc] + u01r * pr - u01i * pi2;
                    ni = ct * ai[cc] + u01r * pi2 + u01i * pr;
                }
                ar[cc] = nr; ai[cc] = ni;
            }
        }
        unsigned short rr[4], ii[4];
#pragma unroll
        for (int cc = 0; cc < 4; ++cc) { rr[cc] = bf16rne(ar[cc]); ii[cc] = bf16rne(ai[cc]); }
        *(uint2*)(g_Urb + lane * 64 + s0) =
            make_uint2((unsigned)rr[0] | ((unsigned)rr[1] << 16),
                       (unsigned)rr[2] | ((unsigned)rr[3] << 16));
        *(uint2*)(g_Uib + lane * 64 + s0) =
            make_uint2((unsigned)ii[0] | ((unsigned)ii[1] << 16),
                       (unsigned)ii[2] | ((unsigned)ii[3] << 16));
    } else if (blockIdx.x == 9) {
        // ---- Zw (transposed [c][t]): wave wid covers channels wid*4..+3
        float zr[6];
#pragma unroll
        for (int q = 0; q < 6; ++q) zr[q] = ((lane >> (5 - q)) & 1) ? -1.f : 1.f;
#pragma unroll
        for (int cc = 0; cc < 4; ++cc) {
            int c = wid * 4 + cc;
            float z = 0.f;
#pragma unroll
            for (int q = 0; q < 6; ++q) z += outw[c * 6 + q] * zr[q];
            g_Zwc[c * 64 + lane] = bf16rne(z);
        }
    } else if (blockIdx.x == 10) {
        if (wid == 0) g_cb[lane] = outb[lane] + resb[lane];
        if (wid == 1 && lane < 48) {   // style angles [b][q]
            int bb = lane / 6, q = lane % 6;
            float a = s2db[q];
#pragma unroll 8
            for (int j = 0; j < 128; ++j) a += style[bb * 128 + j] * s2dw[q * 128 + j];
            g_sang[lane] = tanhf(a) * PI_F;
        }
    }
}

// ---------------------------------------------------------------------------
// Phase B: R0's proven k_main (54 KB LDS -> 2 blocks/CU), verbatim.
static __device__ void phaseB(const float* __restrict__ x,
                              const float* __restrict__ dpb,
                              float* __restrict__ out) {
    __shared__ __attribute__((aligned(16))) float smem[13504];  // 54016 B
    unsigned*             xsu32 = (unsigned*)smem;
    const unsigned short* xsu   = (const unsigned short*)smem;
    float*          convres = smem + 8320;                      // [pix][81]
    float*          fact    = smem;                             // [12][64]
    unsigned short* psi_bf  = (unsigned short*)(smem + 1024);   // [64][72]
    unsigned short* p_bf    = (unsigned short*)(smem + 3328);   // [64][72]

    int tid  = threadIdx.x;
    int lane = tid & 63;                 // pixel within block (== w)
    int wid  = __builtin_amdgcn_readfirstlane(tid >> 6);  // 0..15
    int m    = lane & 15;
    int quad = lane >> 4;

    int p = blockIdx.x * 64 + lane;      // pixel id: b*4096 + h*64 + w
    int b = p >> 12;
    int h = (p >> 6) & 63;
    int w = p & 63;
    const float* xb = x + (b << 18);

    // ---- stage x-tile as bf16
    if (tid < 216) {  // zero halo: 3 rows x 2 cols x 36 uints
        int r3 = tid / 72, rest = tid % 72;
        int half = rest / 36, cp = rest % 36;
        xsu32[(r3 * 66 + half * 65) * 36 + cp] = 0u;
    }
#pragma unroll
    for (int k = 0; k < 6; ++k) {
        int flat = k * 1024 + tid;       // 0..6143 = 3 rows x 32 cpairs x 64 w
        int row  = flat >> 11;
        int rem  = flat & 2047;
        int cp   = rem >> 6;
        int w2   = rem & 63;
        int hh   = h + row - 1;
        float v0 = 0.f, v1 = 0.f;
        if ((unsigned)hh < 64u) {
            const float* px = xb + (hh << 6) + w2;
            v0 = px[(2 * cp) << 12];
            v1 = px[(2 * cp + 1) << 12];
        }
        xsu32[(row * 66 + w2 + 1) * 36 + cp] =
            (unsigned)bf16rne(v0) | ((unsigned)bf16rne(v1) << 16);
    }
    __syncthreads();

    // ---- conv+angle MFMA GEMM
    int mt0 = wid >> 2, nt0 = wid & 3;
    const unsigned short* a0base = xsu + (mt0 * 16 + m) * 72 + quad * 8;
    const unsigned short* b0base = g_Bm + ((nt0 * 18) * 64 + lane) * 8;
    f32x4 acc0 = {0.f, 0.f, 0.f, 0.f};
    f32x4 acc1 = {0.f, 0.f, 0.f, 0.f};
    if (wid < 4) {
        const unsigned short* a1base = xsu + (wid * 16 + m) * 72 + quad * 8;
        const unsigned short* b1base = g_Bm + ((4 * 18) * 64 + lane) * 8;
#pragma unroll
        for (int slab = 0; slab < 18; ++slab) {
            int ij = slab >> 1, i = ij / 3, j = ij - 3 * (ij / 3);
            int aoff = i * 4752 + j * 72 + (slab & 1) * 32;
            bf16x8 a0 = *(const bf16x8*)(a0base + aoff);
            bf16x8 b0 = *(const bf16x8*)(b0base + slab * 512);
            acc0 = __builtin_amdgcn_mfma_f32_16x16x32_bf16(a0, b0, acc0, 0, 0, 0);
            bf16x8 a1 = *(const bf16x8*)(a1base + aoff);
            bf16x8 b1 = *(const bf16x8*)(b1base + slab * 512);
            acc1 = __builtin_amdgcn_mfma_f32_16x16x32_bf16(a1, b1, acc1, 0, 0, 0);
        }
    } else {
#pragma unroll
        for (int slab = 0; slab < 18; ++slab) {
            int ij = slab >> 1, i = ij / 3, j = ij - 3 * (ij / 3);
            int aoff = i * 4752 + j * 72 + (slab & 1) * 32;
            bf16x8 a0 = *(const bf16x8*)(a0base + aoff);
            bf16x8 b0 = *(const bf16x8*)(b0base + slab * 512);
            acc0 = __builtin_amdgcn_mfma_f32_16x16x32_bf16(a0, b0, acc0, 0, 0, 0);
        }
    }
    // C/D layout: col = lane&15 (=n), row = quad*4 + reg (=pixel).
#pragma unroll
    for (int r = 0; r < 4; ++r) {
        convres[(mt0 * 16 + quad * 4 + r) * 81 + nt0 * 16 + m] = acc0[r];
    }
    if (wid < 4) {
#pragma unroll
        for (int r = 0; r < 4; ++r) {
            convres[(wid * 16 + quad * 4 + r) * 81 + 64 + m] = acc1[r];
        }
    }
    __syncthreads();

    // ---- factors: waves 0-5 compute sincos(theta_q/2) for all 64 pixels
    if (wid < 6) {
        int q = wid;
        float t = convres[lane * 81 + 64 + q];
        float theta = tanhf(t + dpb[q]) * PI_F + g_sang[b * 6 + q];
        float sv, cv; sincosf(0.5f * theta, &sv, &cv);
        fact[q * 64 + lane] = sv;
        fact[(6 + q) * 64 + lane] = cv;
    }
    __syncthreads();

    // ---- psi (bf16): each wave builds states 4*wid..4*wid+3 for its pixel
    {
        float f0s = fact[0 * 64 + lane], f0c = fact[6 * 64 + lane];
        float f1s = fact[1 * 64 + lane], f1c = fact[7 * 64 + lane];
        float f2s = fact[2 * 64 + lane], f2c = fact[8 * 64 + lane];
        float f3s = fact[3 * 64 + lane], f3c = fact[9 * 64 + lane];
        float f4s = fact[4 * 64 + lane], f4c = fact[10 * 64 + lane];
        float f5s = fact[5 * 64 + lane], f5c = fact[11 * 64 + lane];
        int sb = wid * 4;
        float pre = (((sb >> 5) & 1) ? f0s : f0c)
                  * (((sb >> 4) & 1) ? f1s : f1c)
                  * (((sb >> 3) & 1) ? f2s : f2c)
                  * (((sb >> 2) & 1) ? f3s : f3c);
        unsigned short pk[4];
#pragma unroll
        for (int ti = 0; ti < 4; ++ti) {
            float v = pre * ((ti & 2) ? f4s : f4c) * ((ti & 1) ? f5s : f5c);
            pk[ti] = bf16rne(v);
        }
        *(uint2*)(psi_bf + lane * 72 + sb) =
            make_uint2((unsigned)pk[0] | ((unsigned)pk[1] << 16),
                       (unsigned)pk[2] | ((unsigned)pk[3] << 16));
    }
    __syncthreads();

    // ---- GEMM 1/2: Yr/Yi[pix][t] = psi[pix][s] @ U[t][s]^T
    {
        const unsigned short* pa = psi_bf + (mt0 * 16 + m) * 72 + quad * 8;
        const unsigned short* ur = g_Urb + (nt0 * 16 + m) * 64 + quad * 8;
        const unsigned short* ui = g_Uib + (nt0 * 16 + m) * 64 + quad * 8;
        bf16x8 aA = *(const bf16x8*)(pa);
        bf16x8 aB = *(const bf16x8*)(pa + 32);
        f32x4 c1 = {0.f, 0.f, 0.f, 0.f};
        f32x4 c2 = {0.f, 0.f, 0.f, 0.f};
        c1 = __builtin_amdgcn_mfma_f32_16x16x32_bf16(aA, *(const bf16x8*)(ur), c1, 0, 0, 0);
        c1 = __builtin_amdgcn_mfma_f32_16x16x32_bf16(aB, *(const bf16x8*)(ur + 32), c1, 0, 0, 0);
        c2 = __builtin_amdgcn_mfma_f32_16x16x32_bf16(aA, *(const bf16x8*)(ui), c2, 0, 0, 0);
        c2 = __builtin_amdgcn_mfma_f32_16x16x32_bf16(aB, *(const bf16x8*)(ui + 32), c2, 0, 0, 0);
#pragma unroll
        for (int r = 0; r < 4; ++r) {
            float pv = c1[r] * c1[r] + c2[r] * c2[r];
            p_bf[(mt0 * 16 + quad * 4 + r) * 72 + nt0 * 16 + m] = bf16rne(pv);
        }
    }
    __syncthreads();

    // ---- GEMM 3: O[pix][c] = P[pix][t] @ Zw[t][c], accumulate into convres
    {
        const unsigned short* pa = p_bf + (mt0 * 16 + m) * 72 + quad * 8;
        const unsigned short* zc = g_Zwc + (nt0 * 16 + m) * 64 + quad * 8;
        f32x4 o = {0.f, 0.f, 0.f, 0.f};
        o = __builtin_amdgcn_mfma_f32_16x16x32_bf16(*(const bf16x8*)(pa),
                                                    *(const bf16x8*)(zc), o, 0, 0, 0);
        o = __builtin_amdgcn_mfma_f32_16x16x32_bf16(*(const bf16x8*)(pa + 32),
                                                    *(const bf16x8*)(zc + 32), o, 0, 0, 0);
#pragma unroll
        for (int r = 0; r < 4; ++r) {
            convres[(mt0 * 16 + quad * 4 + r) * 81 + nt0 * 16 + m] += o[r];
        }
    }
    __syncthreads();

    // ---- coalesced store: each wave stores 4 channels for all 64 pixels
    int ob = (b << 18) + (h << 6) + w;
#pragma unroll
    for (int kk = 0; kk < 4; ++kk) {
        int c = wid * 4 + kk;
        out[ob + (c << 12)] = convres[lane * 81 + c] + g_cb[c];
    }
}

// ---------------------------------------------------------------------------
// Cooperative fused kernel: prep -> grid sync -> main. 512 blocks, 2/CU.
__global__ __launch_bounds__(1024, 8) void k_all(
        const float* __restrict__ x,     const float* __restrict__ style,
        const float* __restrict__ dw,    const float* __restrict__ dpb,
        const float* __restrict__ s2dw,  const float* __restrict__ s2db,
        const float* __restrict__ qcnn,  const float* __restrict__ meas,
        const float* __restrict__ outw,  const float* __restrict__ outb,
        const float* __restrict__ rw,    const float* __restrict__ resb,
        float* __restrict__ out) {
    phaseA(style, dw, rw, s2dw, s2db, qcnn, meas, outw, outb, resb);
    __threadfence();
    cg::this_grid().sync();
    phaseB(x, dpb, out);
}

// Fallback two-dispatch path (proven R0 structure).
__global__ __launch_bounds__(1024) void k_prep_fb(
        const float* __restrict__ style, const float* __restrict__ dw,
        const float* __restrict__ rw,    const float* __restrict__ s2dw,
        const float* __restrict__ s2db,  const float* __restrict__ qcnn,
        const float* __restrict__ meas,  const float* __restrict__ outw,
        const float* __restrict__ outb,  const float* __restrict__ resb) {
    phaseA(style, dw, rw, s2dw, s2db, qcnn, meas, outw, outb, resb);
}

__global__ __launch_bounds__(1024, 4) void k_main_fb(
        const float* __restrict__ x, const float* __restrict__ dpb,
        float* __restrict__ out) {
    phaseB(x, dpb, out);
}

// ---------------------------------------------------------------------------
extern "C" void kernel_launch(void* const* d_in, const int* in_sizes, int n_in,
                              void* d_out, int out_size, void* d_ws, size_t ws_size,
                              hipStream_t stream) {
    const float* x     = (const float*)d_in[0];
    const float* style = (const float*)d_in[1];
    const float* dw    = (const float*)d_in[2];
    const float* dpb   = (const float*)d_in[3];
    const float* s2dw  = (const float*)d_in[4];
    const float* s2db  = (const float*)d_in[5];
    const float* qcnn  = (const float*)d_in[6];
    const float* meas  = (const float*)d_in[7];
    const float* outw  = (const float*)d_in[8];
    const float* outb  = (const float*)d_in[9];
    const float* rw    = (const float*)d_in[10];
    const float* resb  = (const float*)d_in[11];
    float* out = (float*)d_out;

    // One-time check: can 512 blocks of k_all be co-resident (cooperative)?
    static int coop_state = -1;   // -1 unknown, 0 no, 1 yes
    if (coop_state < 0) {
        int dev = 0;
        hipGetDevice(&dev);
        int attr = 0;
        hipDeviceGetAttribute(&attr, hipDeviceAttributeCooperativeLaunch, dev);
        int ncu = 0;
        hipDeviceGetAttribute(&ncu, hipDeviceAttributeMultiprocessorCount, dev);
        int maxb = 0;
        hipOccupancyMaxActiveBlocksPerMultiprocessor(
            &maxb, reinterpret_cast<const void*>(k_all), 1024, 0);
        coop_state = (attr && (long)maxb * ncu >= 512) ? 1 : 0;
    }

    if (coop_state == 1) {
        void* args[] = {(void*)&x, (void*)&style, (void*)&dw, (void*)&dpb,
                        (void*)&s2dw, (void*)&s2db, (void*)&qcnn, (void*)&meas,
                        (void*)&outw, (void*)&outb, (void*)&rw, (void*)&resb,
                        (void*)&out};
        hipError_t e = hipLaunchCooperativeKernel(
            reinterpret_cast<const void*>(k_all), dim3(512), dim3(1024),
            args, 0, stream);
        if (e == hipSuccess) return;
        coop_state = 0;   // fall through to classic path this and future calls
    }

    hipLaunchKernelGGL(k_prep_fb, dim3(11), dim3(1024), 0, stream,
                       style, dw, rw, s2dw, s2db, qcnn, meas, outw, outb, resb);
    hipLaunchKernelGGL(k_main_fb, dim3(512), dim3(1024), 0, stream, x, dpb, out);
}

// Round 4
// 110.297 us; speedup vs baseline: 1.3811x; 1.0380x over previous
//
#include <hip/hip_runtime.h>
#include <math.h>

#define PI_F 3.14159265358979323846f

typedef __attribute__((ext_vector_type(8))) short bf16x8;   // 8 bf16 (4 VGPRs)
typedef __attribute__((ext_vector_type(4))) float f32x4;    // MFMA C/D

// Persistent device tables (rewritten fully on every launch).
__device__ float g_sang[48];       // style angles [b][q] (tanh*pi applied)
__device__ float g_cb[64];         // out_proj_b + res_proj_b
__device__ __attribute__((aligned(16))) unsigned short g_Urb[64 * 64];  // [t][s]
__device__ __attribute__((aligned(16))) unsigned short g_Uib[64 * 64];  // [t][s]
__device__ __attribute__((aligned(16))) unsigned short g_Zwc[64 * 64];  // [c][t]
// MFMA B operand for conv GEMM: [ntile(5)][slab(18)][lane(64)][j(8)]
__device__ __attribute__((aligned(16))) unsigned short g_Bm[5 * 18 * 64 * 8];

__device__ inline unsigned short bf16rne(float f) {
    unsigned u = __float_as_uint(f);
    return (unsigned short)((u + 0x7FFFu + ((u >> 16) & 1u)) >> 16);
}
__device__ inline float rlane(float v, int k) {
    return __uint_as_float(__builtin_amdgcn_readlane(__float_as_uint(v), k));
}

// ---------------------------------------------------------------------------
// k_prep: 8 blocks x 1024 threads.
//   bid 0   : circuit columns (16 waves x 4 cols, lane-parallel trig)
//   bid 1..6: Bm build (5760 fragment entries, 16 B store each)
//   bid 7   : Zw (transposed bf16) + combined bias + style angles
__global__ __launch_bounds__(1024) void k_prep(
        const float* __restrict__ style,
        const float* __restrict__ dw, const float* __restrict__ rw,
        const float* __restrict__ s2dw, const float* __restrict__ s2db,
        const float* __restrict__ qcnn, const float* __restrict__ meas,
        const float* __restrict__ outw, const float* __restrict__ outb,
        const float* __restrict__ resb) {
    int bid  = blockIdx.x;
    int tid  = threadIdx.x;
    int lane = tid & 63;
    int wid  = tid >> 6;

    if (bid >= 1 && bid <= 6) {   // Bm build
        int entry = (bid - 1) * 1024 + tid;
        if (entry < 5760) {
            int nt   = entry / 1152;
            int rem  = entry - nt * 1152;
            int slab = rem >> 6;
            int ln   = rem & 63;
            int mm   = ln & 15, qq = ln >> 4;
            int n    = nt * 16 + mm;
            int ij   = slab >> 1;
            int ch   = (slab & 1) * 32 + qq * 8;
            unsigned pk[4] = {0u, 0u, 0u, 0u};
            if (n < 70) {
                const float* src = (n < 64) ? (rw + n * 576 + ij)
                                            : (dw + (n - 64) * 576 + ij);
#pragma unroll
                for (int jj = 0; jj < 4; ++jj) {
                    pk[jj] = (unsigned)bf16rne(src[(ch + 2 * jj) * 9])
                           | ((unsigned)bf16rne(src[(ch + 2 * jj + 1) * 9]) << 16);
                }
            }
            *(uint4*)(g_Bm + entry * 8) = make_uint4(pk[0], pk[1], pk[2], pk[3]);
        }
        return;
    }

    if (bid == 7) {   // Zw + cb + sang
        float zr[6];
#pragma unroll
        for (int q = 0; q < 6; ++q) zr[q] = ((lane >> (5 - q)) & 1) ? -1.f : 1.f;
#pragma unroll
        for (int cc = 0; cc < 4; ++cc) {
            int c = wid * 4 + cc;
            float z = 0.f;
#pragma unroll
            for (int q = 0; q < 6; ++q) z += outw[c * 6 + q] * zr[q];
            g_Zwc[c * 64 + lane] = bf16rne(z);
        }
        if (wid == 0) g_cb[lane] = outb[lane] + resb[lane];
        if (wid == 1 && lane < 48) {
            int bb = lane / 6, q = lane % 6;
            float a = s2db[q];
#pragma unroll 8
            for (int j = 0; j < 128; ++j) a += style[bb * 128 + j] * s2dw[q * 128 + j];
            g_sang[lane] = tanhf(a) * PI_F;
        }
        return;
    }

    // ---- bid 0: circuit. Lane-parallel trig table, then 4 columns per wave.
    float tsv, tcv;
    {
        int idx = lane < 48 ? lane : 0;
        float arg;
        if (idx < 24) {
            arg = 0.5f * qcnn[idx * 3];
        } else {
            int q3 = (idx - 24) >> 2, part = (idx - 24) & 3;
            float th = meas[q3 * 3 + 0], ph = meas[q3 * 3 + 1], lm = meas[q3 * 3 + 2];
            arg = part == 0 ? 0.5f * th : part == 1 ? lm : part == 2 ? ph : ph + lm;
        }
        sincosf(arg, &tsv, &tcv);
    }
    int s0 = wid * 4;
    float ar[4], ai[4];
#pragma unroll
    for (int cc = 0; cc < 4; ++cc) {
        ar[cc] = (lane == s0 + cc) ? 1.f : 0.f;
        ai[cc] = 0.f;
    }
#pragma unroll
    for (int l = 0; l < 2; ++l) {
#pragma unroll
        for (int wq = 0; wq < 6; ++wq) {
            int mask = 1 << (5 - wq);
            bool hi = (lane & mask) != 0;
            int g = (l * 6 + wq) * 2;
            float sg = rlane(tsv, g),     cg = rlane(tcv, g);
            float sz = rlane(tsv, g + 1), cz = rlane(tcv, g + 1);
            float szz = hi ? sz : -sz;
#pragma unroll
            for (int cc = 0; cc < 4; ++cc) {
                float pr  = __shfl_xor(ar[cc], mask);
                float pi2 = __shfl_xor(ai[cc], mask);
                float nr = hi ? (sg * pr + cg * ar[cc]) : (cg * ar[cc] - sg * pr);
                float ni = hi ? (sg * pi2 + cg * ai[cc]) : (cg * ai[cc] - sg * pi2);
                ar[cc] = cz * nr - szz * ni;
                ai[cc] = cz * ni + szz * nr;
            }
        }
#pragma unroll
        for (int wq = 0; wq < 6; ++wq) {  // ring CNOTs
            int cm = 1 << (5 - wq);
            int tm = 1 << (5 - ((wq + 1) % 6));
#pragma unroll
            for (int cc = 0; cc < 4; ++cc) {
                float pr  = __shfl_xor(ar[cc], tm);
                float pi2 = __shfl_xor(ai[cc], tm);
                if (lane & cm) { ar[cc] = pr; ai[cc] = pi2; }
            }
        }
    }
#pragma unroll
    for (int wq = 0; wq < 6; ++wq) {  // U3 measurement basis
        int mask = 1 << (5 - wq);
        bool hi = (lane & mask) != 0;
        int u = 24 + wq * 4;
        float st2 = rlane(tsv, u),     ct  = rlane(tcv, u);
        float sl  = rlane(tsv, u + 1), cl  = rlane(tcv, u + 1);
        float sp  = rlane(tsv, u + 2), cp  = rlane(tcv, u + 2);
        float spl = rlane(tsv, u + 3), cpl = rlane(tcv, u + 3);
        float u01r = -cl * st2, u01i = -sl * st2;
        float u10r =  cp * st2, u10i =  sp * st2;
        float u11r =  cpl * ct, u11i =  spl * ct;
#pragma unroll
        for (int cc = 0; cc < 4; ++cc) {
            float pr  = __shfl_xor(ar[cc], mask);
            float pi2 = __shfl_xor(ai[cc], mask);
            float nr, ni;
            if (hi) {
                nr = u10r * pr - u10i * pi2 + u11r * ar[cc] - u11i * ai[cc];
                ni = u10r * pi2 + u10i * pr + u11r * ai[cc] + u11i * ar[cc];
            } else {
                nr = ct * ar[cc] + u01r * pr - u01i * pi2;
                ni = ct * ai[cc] + u01r * pi2 + u01i * pr;
            }
            ar[cc] = nr; ai[cc] = ni;
        }
    }
    unsigned short rr[4], ii[4];
#pragma unroll
    for (int cc = 0; cc < 4; ++cc) { rr[cc] = bf16rne(ar[cc]); ii[cc] = bf16rne(ai[cc]); }
    *(uint2*)(g_Urb + lane * 64 + s0) =
        make_uint2((unsigned)rr[0] | ((unsigned)rr[1] << 16),
                   (unsigned)rr[2] | ((unsigned)rr[3] << 16));
    *(uint2*)(g_Uib + lane * 64 + s0) =
        make_uint2((unsigned)ii[0] | ((unsigned)ii[1] << 16),
                   (unsigned)ii[2] | ((unsigned)ii[3] << 16));
}

// ---------------------------------------------------------------------------
// k_main: 512 blocks x 1024 threads = 64 pixels (lane==w) x 16 waves.
// Register-carried conv accumulator: no convres LDS buffer, direct f32x4 store.
// LDS (floats): [0,7128) xs bf16 [3][66][72]; overlays after conv:
//   fact [0,768), psi_bf [1024,3328), p_bf [3328,5632); angs [7128,7640).
__global__ __launch_bounds__(1024, 8) void k_main(const float* __restrict__ x,
                                                  const float* __restrict__ dpb,
                                                  float* __restrict__ out) {
    __shared__ __attribute__((aligned(16))) float smem[7640];   // 30560 B
    unsigned*             xsu32 = (unsigned*)smem;
    const unsigned short* xsu   = (const unsigned short*)smem;
    float*          fact    = smem;                             // [12][64]
    unsigned short* psi_bf  = (unsigned short*)(smem + 1024);   // [64][72]
    unsigned short* p_bf    = (unsigned short*)(smem + 3328);   // [64][72]
    float*          angs    = smem + 7128;                      // [64][8]

    int tid  = threadIdx.x;
    int lane = tid & 63;                 // pixel within block (== w)
    int wid  = __builtin_amdgcn_readfirstlane(tid >> 6);  // 0..15
    int m    = lane & 15;
    int quad = lane >> 4;

    int p = blockIdx.x * 64 + lane;      // pixel id: b*4096 + h*64 + w
    int b = p >> 12;                     // block-uniform
    int h = (p >> 6) & 63;               // block-uniform
    const float* xb = x + (b << 18);

    // ---- stage x-tile as bf16
    if (tid < 216) {  // zero halo: 3 rows x 2 cols x 36 uints
        int r3 = tid / 72, rest = tid % 72;
        int half = rest / 36, cp = rest % 36;
        xsu32[(r3 * 66 + half * 65) * 36 + cp] = 0u;
    }
#pragma unroll
    for (int k = 0; k < 6; ++k) {
        int flat = k * 1024 + tid;       // 0..6143 = 3 rows x 32 cpairs x 64 w
        int row  = flat >> 11;
        int rem  = flat & 2047;
        int cp   = rem >> 6;
        int w2   = rem & 63;
        int hh   = h + row - 1;
        float v0 = 0.f, v1 = 0.f;
        if ((unsigned)hh < 64u) {
            const float* px = xb + (hh << 6) + w2;
            v0 = px[(2 * cp) << 12];
            v1 = px[(2 * cp + 1) << 12];
        }
        xsu32[(row * 66 + w2 + 1) * 36 + cp] =
            (unsigned)bf16rne(v0) | ((unsigned)bf16rne(v1) << 16);
    }
    __syncthreads();   // B1

    // ---- conv+angle MFMA GEMM (A: LDS, B: g_Bm global/L2)
    int mt0 = wid >> 2, nt0 = wid & 3;
    const unsigned short* a0base = xsu + (mt0 * 16 + m) * 72 + quad * 8;
    const unsigned short* b0base = g_Bm + ((nt0 * 18) * 64 + lane) * 8;
    f32x4 acc0 = {0.f, 0.f, 0.f, 0.f};
    f32x4 acc1 = {0.f, 0.f, 0.f, 0.f};
    if (wid < 4) {
        const unsigned short* a1base = xsu + (wid * 16 + m) * 72 + quad * 8;
        const unsigned short* b1base = g_Bm + ((4 * 18) * 64 + lane) * 8;
#pragma unroll
        for (int slab = 0; slab < 18; ++slab) {
            int ij = slab >> 1, i = ij / 3, j = ij - 3 * (ij / 3);
            int aoff = i * 4752 + j * 72 + (slab & 1) * 32;
            bf16x8 a0 = *(const bf16x8*)(a0base + aoff);
            bf16x8 b0 = *(const bf16x8*)(b0base + slab * 512);
            acc0 = __builtin_amdgcn_mfma_f32_16x16x32_bf16(a0, b0, acc0, 0, 0, 0);
            bf16x8 a1 = *(const bf16x8*)(a1base + aoff);
            bf16x8 b1 = *(const bf16x8*)(b1base + slab * 512);
            acc1 = __builtin_amdgcn_mfma_f32_16x16x32_bf16(a1, b1, acc1, 0, 0, 0);
        }
    } else {
#pragma unroll
        for (int slab = 0; slab < 18; ++slab) {
            int ij = slab >> 1, i = ij / 3, j = ij - 3 * (ij / 3);
            int aoff = i * 4752 + j * 72 + (slab & 1) * 32;
            bf16x8 a0 = *(const bf16x8*)(a0base + aoff);
            bf16x8 b0 = *(const bf16x8*)(b0base + slab * 512);
            acc0 = __builtin_amdgcn_mfma_f32_16x16x32_bf16(a0, b0, acc0, 0, 0, 0);
        }
    }
    // angle columns (acc1, m<6) -> angs[pix][q]; angs is outside xs, no race.
    if (wid < 4 && m < 6) {
#pragma unroll
        for (int r = 0; r < 4; ++r) {
            angs[(wid * 16 + quad * 4 + r) * 8 + m] = acc1[r];
        }
    }
    __syncthreads();   // B2 (conv done: xs dead, angs visible)

    // ---- factors: waves 0-5 compute sincos(theta_q/2) for all 64 pixels
    if (wid < 6) {
        int q = wid;
        float tv = angs[lane * 8 + q];
        float theta = tanhf(tv + dpb[q]) * PI_F + g_sang[b * 6 + q];
        float sv, cv; sincosf(0.5f * theta, &sv, &cv);
        fact[q * 64 + lane] = sv;
        fact[(6 + q) * 64 + lane] = cv;
    }
    __syncthreads();   // B3

    // ---- psi (bf16): each wave builds states 4*wid..4*wid+3 for its pixel
    {
        float f0s = fact[0 * 64 + lane], f0c = fact[6 * 64 + lane];
        float f1s = fact[1 * 64 + lane], f1c = fact[7 * 64 + lane];
        float f2s = fact[2 * 64 + lane], f2c = fact[8 * 64 + lane];
        float f3s = fact[3 * 64 + lane], f3c = fact[9 * 64 + lane];
        float f4s = fact[4 * 64 + lane], f4c = fact[10 * 64 + lane];
        float f5s = fact[5 * 64 + lane], f5c = fact[11 * 64 + lane];
        int sb = wid * 4;
        float pre = (((sb >> 5) & 1) ? f0s : f0c)
                  * (((sb >> 4) & 1) ? f1s : f1c)
                  * (((sb >> 3) & 1) ? f2s : f2c)
                  * (((sb >> 2) & 1) ? f3s : f3c);
        unsigned short pk[4];
#pragma unroll
        for (int ti = 0; ti < 4; ++ti) {
            float v = pre * ((ti & 2) ? f4s : f4c) * ((ti & 1) ? f5s : f5c);
            pk[ti] = bf16rne(v);
        }
        *(uint2*)(psi_bf + lane * 72 + sb) =
            make_uint2((unsigned)pk[0] | ((unsigned)pk[1] << 16),
                       (unsigned)pk[2] | ((unsigned)pk[3] << 16));
    }
    __syncthreads();   // B4

    // ---- GEMM 1/2: Yr/Yi[pix][t] = psi[pix][s] @ U[t][s]^T
    {
        const unsigned short* pa = psi_bf + (mt0 * 16 + m) * 72 + quad * 8;
        const unsigned short* ur = g_Urb + (nt0 * 16 + m) * 64 + quad * 8;
        const unsigned short* ui = g_Uib + (nt0 * 16 + m) * 64 + quad * 8;
        bf16x8 aA = *(const bf16x8*)(pa);
        bf16x8 aB = *(const bf16x8*)(pa + 32);
        f32x4 c1 = {0.f, 0.f, 0.f, 0.f};
        f32x4 c2 = {0.f, 0.f, 0.f, 0.f};
        c1 = __builtin_amdgcn_mfma_f32_16x16x32_bf16(aA, *(const bf16x8*)(ur), c1, 0, 0, 0);
        c1 = __builtin_amdgcn_mfma_f32_16x16x32_bf16(aB, *(const bf16x8*)(ur + 32), c1, 0, 0, 0);
        c2 = __builtin_amdgcn_mfma_f32_16x16x32_bf16(aA, *(const bf16x8*)(ui), c2, 0, 0, 0);
        c2 = __builtin_amdgcn_mfma_f32_16x16x32_bf16(aB, *(const bf16x8*)(ui + 32), c2, 0, 0, 0);
#pragma unroll
        for (int r = 0; r < 4; ++r) {
            float pv = c1[r] * c1[r] + c2[r] * c2[r];
            p_bf[(mt0 * 16 + quad * 4 + r) * 72 + nt0 * 16 + m] = bf16rne(pv);
        }
    }
    __syncthreads();   // B5

    // ---- GEMM 3: O[pix][c] = P[pix][t] @ Zw[t][c]; fuse add + direct store.
    {
        const unsigned short* pa = p_bf + (mt0 * 16 + m) * 72 + quad * 8;
        const unsigned short* zc = g_Zwc + (nt0 * 16 + m) * 64 + quad * 8;
        f32x4 o = {0.f, 0.f, 0.f, 0.f};
        o = __builtin_amdgcn_mfma_f32_16x16x32_bf16(*(const bf16x8*)(pa),
                                                    *(const bf16x8*)(zc), o, 0, 0, 0);
        o = __builtin_amdgcn_mfma_f32_16x16x32_bf16(*(const bf16x8*)(pa + 32),
                                                    *(const bf16x8*)(zc + 32), o, 0, 0, 0);
        // This wave's G3 quadrant == its conv acc0 quadrant:
        //   row (pixel/w) = mt0*16 + quad*4 + r, col (channel) = nt0*16 + m.
        int cch = nt0 * 16 + m;
        float cbv = g_cb[cch];
        float4 res;
        res.x = (acc0[0] + o[0]) + cbv;
        res.y = (acc0[1] + o[1]) + cbv;
        res.z = (acc0[2] + o[2]) + cbv;
        res.w = (acc0[3] + o[3]) + cbv;
        int base = (b << 18) + (cch << 12) + (h << 6) + mt0 * 16 + quad * 4;
        *(float4*)(out + base) = res;   // 16 B/lane, 64 B contiguous per channel
    }
}

// ---------------------------------------------------------------------------
extern "C" void kernel_launch(void* const* d_in, const int* in_sizes, int n_in,
                              void* d_out, int out_size, void* d_ws, size_t ws_size,
                              hipStream_t stream) {
    const float* x     = (const float*)d_in[0];
    const float* style = (const float*)d_in[1];
    const float* dw    = (const float*)d_in[2];
    const float* dpb   = (const float*)d_in[3];
    const float* s2dw  = (const float*)d_in[4];
    const float* s2db  = (const float*)d_in[5];
    const float* qcnn  = (const float*)d_in[6];
    const float* meas  = (const float*)d_in[7];
    const float* outw  = (const float*)d_in[8];
    const float* outb  = (const float*)d_in[9];
    const float* rw    = (const float*)d_in[10];
    const float* resb  = (const float*)d_in[11];
    float* out = (float*)d_out;

    hipLaunchKernelGGL(k_prep, dim3(8), dim3(1024), 0, stream,
                       style, dw, rw, s2dw, s2db, qcnn, meas, outw, outb, resb);
    hipLaunchKernelGGL(k_main, dim3(512), dim3(1024), 0, stream, x, dpb, out);
}